// Round 9
// baseline (101.248 us; speedup 1.0000x reference)
//
#include <hip/hip_runtime.h>
#include <math.h>
#include <limits.h>

#define IN_FEATURES 1024
#define OUT_FEATURES 512
#define N_PULSE 10
#define NCOL 1034
#define BATCH 32
#define MIN_W_ARG -0.3678794411714423

#define NSEG 16
#define SEG 66                          /* 16*66 = 1056 scan steps */
#define TBLN 1088                       /* table entries (>= 1056+1, 16-mult) */

/* packed per-b table: [ord i32 TBLN][ts f32 TBLN][z f64 TBLN][zt f64 TBLN] */
#define OFF_TS  (TBLN * 4)
#define OFF_Z   (TBLN * 8)
#define OFF_ZT  (TBLN * 16)
#define TBL_BYTES (TBLN * 24)           /* 26112 */

#define PREP_T_BLOCKS 136               /* 17 n-tiles x 8 o-tiles */
#define PREP_BLOCKS (PREP_T_BLOCKS + BATCH)

/* rank-block LDS layout (bytes) */
#define R_KM   0                        /* u32 monotone keys [1034] */
#define R_KF   4136                     /* f32 t             [1034] */
#define R_SIDX 8272                     /* i32 slot->elem    [1034] */
#define R_BASE 12408                    /* i32 bucket base   [1025] */
#define R_RUN  16508                    /* i32 running ptr   [1024] */
#define R_PS   20604                    /* i32 scan temp     [256]  */
#define R_BYTES 21632

// ---------- Kernel 1 (prep): transpose | counting-sort rank + z tables -------
__global__ __launch_bounds__(256, 1) void prep_kernel(
        const float* __restrict__ w, float* __restrict__ wT,
        const float* __restrict__ x, const float* __restrict__ pulse,
        char* __restrict__ tbl) {
    __shared__ __align__(16) char smem_u[R_BYTES];   // >= transpose tile 16640
    const int tid = threadIdx.x;

    if (blockIdx.x < PREP_T_BLOCKS) {
        // ---- tiled transpose [O,N] -> [N,O], coalesced both ways ----
        float (*tile)[65] = (float (*)[65])smem_u;
        const int n0 = (blockIdx.x % 17) * 64;
        const int o0 = (blockIdx.x / 17) * 64;
        const int tx = tid & 63, ty = tid >> 6;
        #pragma unroll
        for (int r = 0; r < 16; ++r) {
            int ol = r * 4 + ty, n = n0 + tx;
            if (n < NCOL) tile[ol][tx] = w[(o0 + ol) * NCOL + n];
        }
        __syncthreads();
        #pragma unroll
        for (int r = 0; r < 16; ++r) {
            int nl = r * 4 + ty, n = n0 + nl;
            if (n < NCOL) wT[n * OUT_FEATURES + o0 + tx] = tile[tx][nl];
        }
    } else {
        // ---- counting-sort stable argsort for batch row b ----
        unsigned*  km   = (unsigned*)(smem_u + R_KM);
        float*     kf   = (float*)(smem_u + R_KF);
        int*       sidx = (int*)(smem_u + R_SIDX);
        int*       base = (int*)(smem_u + R_BASE);
        int*       run  = (int*)(smem_u + R_RUN);
        int*       ps   = (int*)(smem_u + R_PS);
        const int b = blockIdx.x - PREP_T_BLOCKS;

        for (int e = tid; e < NCOL; e += 256) {
            float t = (e < IN_FEATURES) ? x[b * IN_FEATURES + e]
                                        : pulse[e - IN_FEATURES];
            kf[e] = t;
            unsigned u = __float_as_uint(t);
            km[e] = (u & 0x80000000u) ? ~u : (u | 0x80000000u);
        }
        for (int i = tid; i < 1024; i += 256) run[i] = 0;
        __syncthreads();

        // histogram: bucket(t) = min(1023, t*1024) is monotone in t
        for (int e = tid; e < NCOL; e += 256) {
            int bk = min(1023, max(0, (int)(kf[e] * 1024.0f)));
            atomicAdd(&run[bk], 1);
        }
        __syncthreads();

        // exclusive prefix over 1024 counts (4 per thread + block scan)
        int c4[4], v = 0;
        #pragma unroll
        for (int j = 0; j < 4; ++j) { c4[j] = run[4 * tid + j]; v += c4[j]; }
        ps[tid] = v;
        __syncthreads();
        for (int off = 1; off < 256; off <<= 1) {
            int xv = (tid >= off) ? ps[tid - off] : 0;
            __syncthreads();
            ps[tid] += xv;
            __syncthreads();
        }
        int ex = ps[tid] - v;
        #pragma unroll
        for (int j = 0; j < 4; ++j) { base[4 * tid + j] = ex; ex += c4[j]; }
        if (tid == 255) base[1024] = ex;            // == NCOL
        __syncthreads();
        for (int i = tid; i < 1024; i += 256) run[i] = base[i];
        __syncthreads();

        // scatter (arbitrary intra-bucket order)
        for (int e = tid; e < NCOL; e += 256) {
            int bk = min(1023, max(0, (int)(kf[e] * 1024.0f)));
            int slot = atomicAdd(&run[bk], 1);
            sidx[slot] = e;
        }
        __syncthreads();

        // exact stable rank within bucket + global table write
        char* gb = tbl + b * TBL_BYTES;
        int*    ordg = (int*)gb;
        float*  tsg  = (float*)(gb + OFF_TS);
        double* zg   = (double*)(gb + OFF_Z);
        double* ztg  = (double*)(gb + OFF_ZT);

        for (int s = tid; s < NCOL; s += 256) {
            int e = sidx[s];
            float t = kf[e];
            unsigned u = km[e];
            int bk = min(1023, max(0, (int)(t * 1024.0f)));
            int lo = base[bk], hi = base[bk + 1];
            int r = lo;
            for (int j = lo; j < hi; ++j) {         // avg 1 element per bucket
                int ej = sidx[j];
                unsigned uj = km[ej];
                r += (uj < u) || (uj == u && ej < e);
            }
            double zv = exp((double)t);
            ordg[r] = e; tsg[r] = t; zg[r] = zv; ztg[r] = zv * (double)t;
        }
        for (int p = NCOL + tid; p < TBLN; p += 256) {
            ordg[p] = 0; tsg[p] = -1.0f; zg[p] = 0.0; ztg[p] = 0.0;
            // pad ts=-1: scan's fire test provably false on pad steps
        }
    }
}

// ------------------------- Lambert W0 on [-1/e, 0] ---------------------------
__device__ __forceinline__ double lambertw0(double xx) {
    const double e = 2.718281828459045;
    double w = (xx < -0.25) ? (-1.0 + sqrt(fmax(2.0 * (1.0 + e * xx), 0.0)))
                            : xx * (1.0 - xx);
    #pragma unroll 4
    for (int i = 0; i < 12; ++i) {
        double ew = exp(w);
        double f  = w * ew - xx;
        double denom = ew * (w + 1.0) - (w + 2.0) * f / (2.0 * (w + 1.0) + 1e-12);
        w = w - f / (denom + 1e-12);
    }
    return w;
}

// ------------- Kernel 2: segmented two-pass scan, scalar-pipe tables ---------
// Per-(b,k) table values (ord, ts, z, zt) are wave-uniform -> read from GLOBAL
// with uniform indices so they land in SGPRs via s_load (scalar cache), not
// the per-CU DS pipe (R7/R8's bottleneck: ~6700 ds_reads/CU serialized).
// Weight gather: SGPR base (readfirstlane(ord)*row) + fixed VGPR offset o*4.
// pass1: per-segment (dA,dB); pass2: rescan with exclusive prefix, first fire
// (fire = A>1e-10 && A*t_{k+1}-B >= z_{k+1}); final: wave 0 earliest fire,
// ONE Lambert + exact reference check; exact serial fallback (never taken).
__global__ __launch_bounds__(1024) void solve_kernel(
        const float* __restrict__ wT,
        const char* __restrict__ tbl,
        float* __restrict__ out) {
    __shared__ double segA[NSEG * 64], segB[NSEG * 64];
    __shared__ int    sfk[NSEG * 64];
    __shared__ double sfA[NSEG * 64], sfB[NSEG * 64];

    const int b = blockIdx.x >> 3;
    const int o0 = (blockIdx.x & 7) << 6;
    const int wave = threadIdx.x >> 6;
    const int lane = threadIdx.x & 63;
    const int o = o0 + lane;

    const char* base = tbl + b * TBL_BYTES;
    const int*    ordg = (const int*)base;
    const float*  tsg  = (const float*)(base + OFF_TS);
    const double* zg   = (const double*)(base + OFF_Z);
    const double* ztg  = (const double*)(base + OFF_ZT);

    const int k0 = wave * SEG;

    // ---- pass 1: segment partial sums ----
    {
        double a0 = 0.0, a1 = 0.0, b0 = 0.0, b1 = 0.0;
        for (int c = 0; c < SEG; c += 11) {
            float buf[11];
            #pragma unroll
            for (int i = 0; i < 11; ++i) {
                int idx = __builtin_amdgcn_readfirstlane(ordg[k0 + c + i]);
                buf[i] = wT[idx * OUT_FEATURES + o];      // SGPR base + v(o*4)
            }
            #pragma unroll
            for (int i = 0; i < 11; ++i) {
                double w = (double)buf[i];
                if (i & 1) { a1 = fma(w, zg[k0 + c + i], a1);
                             b1 = fma(w, ztg[k0 + c + i], b1); }
                else       { a0 = fma(w, zg[k0 + c + i], a0);
                             b0 = fma(w, ztg[k0 + c + i], b0); }
            }
        }
        segA[wave * 64 + lane] = a0 + a1;
        segB[wave * 64 + lane] = b0 + b1;
    }
    __syncthreads();

    // ---- pass 2: rescan own segment with exclusive prefix offset ----
    {
        double A = 0.0, Bv = 0.0;
        for (int s = 0; s < wave; ++s) {
            A  += segA[s * 64 + lane];
            Bv += segB[s * 64 + lane];
        }
        int fk = INT_MAX; double fA = 0.0, fB = 0.0;
        for (int c = 0; c < SEG; c += 11) {
            float buf[11];
            #pragma unroll
            for (int i = 0; i < 11; ++i) {
                int idx = __builtin_amdgcn_readfirstlane(ordg[k0 + c + i]);
                buf[i] = wT[idx * OUT_FEATURES + o];
            }
            #pragma unroll
            for (int i = 0; i < 11; ++i) {
                int k = k0 + c + i;
                double w = (double)buf[i];
                A  = fma(w, zg[k],  A);
                Bv = fma(w, ztg[k], Bv);
                bool fire = (fk == INT_MAX) & (A > 1e-10) &
                            (fma(A, (double)tsg[k + 1], -Bv) >= zg[k + 1]);
                if (fire) { fk = k; fA = A; fB = Bv; }
            }
        }
        sfk[wave * 64 + lane] = fk;
        sfA[wave * 64 + lane] = fA;
        sfB[wave * 64 + lane] = fB;
    }
    __syncthreads();

    // ---- final: wave 0, one lane per o ----
    if (wave == 0) {
        int gk = INT_MAX; double gA = 0.0, gB = 0.0;
        #pragma unroll
        for (int s = 0; s < NSEG; ++s) {
            int k = sfk[s * 64 + lane];
            if (k < gk) { gk = k; gA = sfA[s * 64 + lane]; gB = sfB[s * 64 + lane]; }
        }
        bool done = (gk < NCOL);

        double AA, BB, tk, tn;
        bool have;
        if (done) {
            AA = gA; BB = gB;
            tk = (double)tsg[gk];
            tn = (double)tsg[gk + 1];
            have = true;
        } else {
            double tA = 0.0, tB = 0.0;
            #pragma unroll
            for (int s = 0; s < NSEG; ++s) { tA += segA[s * 64 + lane]; tB += segB[s * 64 + lane]; }
            AA = tA; BB = tB;
            tk = (double)tsg[NCOL - 1];
            tn = 1000.0;
            have = (AA > 1e-10);
        }

        float result = 1000.0f;
        bool need_fb = false;
        if (have) {
            double boa = BB / AA;
            double arg = -exp(fmin(boa, 80.0)) / AA;
            if (arg >= MIN_W_ARG) {
                double wl = lambertw0(fmin(fmax(arg, MIN_W_ARG), 0.0));
                double tc = boa - wl;
                if (tc >= tk && tc <= tn) result = (float)tc;
                else need_fb = done;
            } else need_fb = done;
        }

        // exact serial fallback (fp-boundary safety net; never taken)
        if (__ballot(need_fb) != 0ULL) {
            double A2 = gA, B2 = gB;
            for (int k = gk + 1; k < NCOL && k >= 0; ++k) {
                if (!need_fb) break;
                double w = (double)wT[ordg[k] * OUT_FEATURES + o];
                A2 = fma(w, zg[k], A2);
                B2 = fma(w, ztg[k], B2);
                if (!(A2 > 1e-10)) continue;
                double tkk = (double)tsg[k];
                double tnn = (k == NCOL - 1) ? 1000.0 : (double)tsg[k + 1];
                double boa = B2 / A2;
                double arg = -exp(fmin(boa, 80.0)) / A2;
                if (arg >= MIN_W_ARG) {
                    double wl = lambertw0(fmin(fmax(arg, MIN_W_ARG), 0.0));
                    double tc = boa - wl;
                    if (tc >= tkk && tc <= tnn) { result = (float)tc; need_fb = false; }
                }
            }
        }
        out[b * OUT_FEATURES + o] = result;
    }
}

// --------------------------------- launcher ----------------------------------
extern "C" void kernel_launch(void* const* d_in, const int* in_sizes, int n_in,
                              void* d_out, int out_size, void* d_ws, size_t ws_size,
                              hipStream_t stream) {
    const float* x      = (const float*)d_in[0];
    const float* weight = (const float*)d_in[1];
    const float* pulse  = (const float*)d_in[2];
    float* out = (float*)d_out;

    char* ws = (char*)d_ws;
    float* wT = (float*)ws;                               // 1034*512*4 B
    char*  tbl = ws + (size_t)NCOL * OUT_FEATURES * 4;    // 32 * 26112 B

    hipLaunchKernelGGL(prep_kernel, dim3(PREP_BLOCKS), dim3(256), 0, stream,
                       weight, wT, x, pulse, tbl);
    hipLaunchKernelGGL(solve_kernel, dim3(BATCH * OUT_FEATURES / 64), dim3(1024), 0, stream,
                       wT, tbl, out);
}

// Round 10
// 89.839 us; speedup vs baseline: 1.1270x; 1.1270x over previous
//
#include <hip/hip_runtime.h>
#include <math.h>
#include <limits.h>

#define IN_FEATURES 1024
#define OUT_FEATURES 512
#define N_PULSE 10
#define NCOL 1034
#define BATCH 32
#define MIN_W_ARG -0.3678794411714423

#define NSEG 16
#define SEG 66                          /* 16*66 = 1056 scan steps */
#define TBLN 1088

/* packed per-b table:
   [ord i32][ts f32][z f64][zt f64][zdt double2 (z_k,dt_k)][zfire f64] */
#define OFF_TS   (TBLN * 4)             /* 4352  */
#define OFF_Z    (TBLN * 8)             /* 8704  */
#define OFF_ZT   (TBLN * 16)            /* 17408 */
#define OFF_ZDT  (TBLN * 24)            /* 26112 */
#define OFF_ZF   (TBLN * 40)            /* 43520 */
#define TBL_BYTES (TBLN * 48)           /* 52224 */

#define PREP_T_BLOCKS 136               /* 17 n-tiles x 8 o-tiles */
#define PREP_BLOCKS (PREP_T_BLOCKS + BATCH)

/* rank-block LDS layout (bytes) */
#define R_KM   0
#define R_KF   4136
#define R_SIDX 8272
#define R_BASE 12408
#define R_RUN  16508
#define R_PS   20604
#define R_BYTES 21632

// ---------- Kernel 1 (prep): transpose | counting-sort rank + scan tables ----
__global__ __launch_bounds__(256, 1) void prep_kernel(
        const float* __restrict__ w, float* __restrict__ wT,
        const float* __restrict__ x, const float* __restrict__ pulse,
        char* __restrict__ tbl) {
    __shared__ __align__(16) char smem_u[R_BYTES];
    const int tid = threadIdx.x;

    if (blockIdx.x < PREP_T_BLOCKS) {
        float (*tile)[65] = (float (*)[65])smem_u;
        const int n0 = (blockIdx.x % 17) * 64;
        const int o0 = (blockIdx.x / 17) * 64;
        const int tx = tid & 63, ty = tid >> 6;
        #pragma unroll
        for (int r = 0; r < 16; ++r) {
            int ol = r * 4 + ty, n = n0 + tx;
            if (n < NCOL) tile[ol][tx] = w[(o0 + ol) * NCOL + n];
        }
        __syncthreads();
        #pragma unroll
        for (int r = 0; r < 16; ++r) {
            int nl = r * 4 + ty, n = n0 + nl;
            if (n < NCOL) wT[n * OUT_FEATURES + o0 + tx] = tile[tx][nl];
        }
    } else {
        unsigned*  km   = (unsigned*)(smem_u + R_KM);
        float*     kf   = (float*)(smem_u + R_KF);
        int*       sidx = (int*)(smem_u + R_SIDX);
        int*       base = (int*)(smem_u + R_BASE);
        int*       run  = (int*)(smem_u + R_RUN);
        int*       ps   = (int*)(smem_u + R_PS);
        const int b = blockIdx.x - PREP_T_BLOCKS;

        for (int e = tid; e < NCOL; e += 256) {
            float t = (e < IN_FEATURES) ? x[b * IN_FEATURES + e]
                                        : pulse[e - IN_FEATURES];
            kf[e] = t;
            unsigned u = __float_as_uint(t);
            km[e] = (u & 0x80000000u) ? ~u : (u | 0x80000000u);
        }
        for (int i = tid; i < 1024; i += 256) run[i] = 0;
        __syncthreads();

        for (int e = tid; e < NCOL; e += 256) {
            int bk = min(1023, max(0, (int)(kf[e] * 1024.0f)));
            atomicAdd(&run[bk], 1);
        }
        __syncthreads();

        int c4[4], v = 0;
        #pragma unroll
        for (int j = 0; j < 4; ++j) { c4[j] = run[4 * tid + j]; v += c4[j]; }
        ps[tid] = v;
        __syncthreads();
        for (int off = 1; off < 256; off <<= 1) {
            int xv = (tid >= off) ? ps[tid - off] : 0;
            __syncthreads();
            ps[tid] += xv;
            __syncthreads();
        }
        int ex = ps[tid] - v;
        #pragma unroll
        for (int j = 0; j < 4; ++j) { base[4 * tid + j] = ex; ex += c4[j]; }
        if (tid == 255) base[1024] = ex;
        __syncthreads();
        for (int i = tid; i < 1024; i += 256) run[i] = base[i];
        __syncthreads();

        for (int e = tid; e < NCOL; e += 256) {
            int bk = min(1023, max(0, (int)(kf[e] * 1024.0f)));
            int slot = atomicAdd(&run[bk], 1);
            sidx[slot] = e;
        }
        __syncthreads();

        char* gb = tbl + b * TBL_BYTES;
        int*    ordg = (int*)gb;
        float*  tsg  = (float*)(gb + OFF_TS);
        double* zg   = (double*)(gb + OFF_Z);
        double* ztg  = (double*)(gb + OFF_ZT);

        for (int s = tid; s < NCOL; s += 256) {
            int e = sidx[s];
            float t = kf[e];
            unsigned u = km[e];
            int bk = min(1023, max(0, (int)(t * 1024.0f)));
            int lo = base[bk], hi = base[bk + 1];
            int r = lo;
            for (int j = lo; j < hi; ++j) {
                int ej = sidx[j];
                unsigned uj = km[ej];
                r += (uj < u) || (uj == u && ej < e);
            }
            double zv = exp((double)t);
            ordg[r] = e; tsg[r] = t; zg[r] = zv; ztg[r] = zv * (double)t;
        }
        for (int p = NCOL + tid; p < TBLN; p += 256) {
            ordg[p] = 0; tsg[p] = -1.0f; zg[p] = 0.0; ztg[p] = 0.0;
        }
        __threadfence_block();
        __syncthreads();

        // phase 2: packed scan tables (z_k, dt_k) + zfire = z_{k+1} (inf past end)
        double2* zdtg = (double2*)(gb + OFF_ZDT);
        double*  zfg  = (double*)(gb + OFF_ZF);
        for (int r = tid; r < TBLN; r += 256) {
            double zr = zg[r];
            double dt, zf;
            if (r < NCOL - 1)      { dt = (double)tsg[r + 1] - (double)tsg[r]; zf = zg[r + 1]; }
            else if (r == NCOL - 1){ dt = 1000.0 - (double)tsg[r];             zf = 1e300; }
            else                   { dt = 0.0;                                 zf = 1e300; }
            double2 zd; zd.x = zr; zd.y = dt;
            zdtg[r] = zd;
            zfg[r]  = zf;
        }
    }
}

// ------------------------- Lambert W0 on [-1/e, 0] ---------------------------
__device__ __forceinline__ double lambertw0(double xx) {
    const double e = 2.718281828459045;
    double w = (xx < -0.25) ? (-1.0 + sqrt(fmax(2.0 * (1.0 + e * xx), 0.0)))
                            : xx * (1.0 - xx);
    #pragma unroll 4
    for (int i = 0; i < 12; ++i) {
        double ew = exp(w);
        double f  = w * ew - xx;
        double denom = ew * (w + 1.0) - (w + 2.0) * f / (2.0 * (w + 1.0) + 1e-12);
        w = w - f / (denom + 1e-12);
    }
    return w;
}

// ---- Kernel 2: segmented scan, P-recurrence, SGPR table reads ---------------
// P_k = A_k*t_{k+1} - B_k;  A += w*z_k; P += A*dt_k; fire <=> A>1e-10 && P>=z_{k+1}.
// All table indices derive from readfirstlane(wave) -> provably SGPR -> s_load
// through the scalar cache (R9's failure: VGPR wave id forced vector loads;
// R8's: per-step DS broadcasts saturated the one DS pipe/CU).
// B is reconstructed only at the firing k: B = A*t_{k+1} - P.
__global__ __launch_bounds__(1024) void solve_kernel(
        const float* __restrict__ wT,
        const char* __restrict__ tbl,
        float* __restrict__ out) {
    __shared__ double dAx[NSEG * 64], dPx[NSEG * 64];
    __shared__ int    fkx[NSEG * 64];
    __shared__ double fAx[NSEG * 64], fPx[NSEG * 64];
    __shared__ double endA[64], endP[64];

    const int b = blockIdx.x >> 3;
    const int o0 = (blockIdx.x & 7) << 6;
    const int tid = threadIdx.x;
    const int waveu = __builtin_amdgcn_readfirstlane(tid >> 6);   // SGPR wave id
    const int lane = tid & 63;
    const int o = o0 + lane;

    const char* base = tbl + b * TBL_BYTES;
    const int*     ordg = (const int*)base;
    const float*   tsg  = (const float*)(base + OFF_TS);
    const double*  zg   = (const double*)(base + OFF_Z);
    const double*  ztg  = (const double*)(base + OFF_ZT);
    const double2* zdtg = (const double2*)(base + OFF_ZDT);
    const double*  zfg  = (const double*)(base + OFF_ZF);

    const int k0 = waveu * SEG;

    // ---- pass 1: segment-local (dA, dP) ----
    {
        double a = 0.0, p = 0.0;
        for (int c = 0; c < SEG; c += 11) {
            int so[11]; float buf[11]; double zc[11], dtc[11];
            #pragma unroll
            for (int i = 0; i < 11; ++i) so[i] = ordg[k0 + c + i];       // s_load
            #pragma unroll
            for (int i = 0; i < 11; ++i) buf[i] = wT[so[i] * OUT_FEATURES + o];
            #pragma unroll
            for (int i = 0; i < 11; ++i) { double2 zd = zdtg[k0 + c + i]; // s_load
                                           zc[i] = zd.x; dtc[i] = zd.y; }
            #pragma unroll
            for (int i = 0; i < 11; ++i) {
                double w = (double)buf[i];
                a = fma(w, zc[i], a);
                p = fma(a, dtc[i], p);
            }
        }
        dAx[waveu * 64 + lane] = a;
        dPx[waveu * 64 + lane] = p;
    }
    __syncthreads();

    // ---- pass 2: rescan with exclusive prefix; record first fire ----
    {
        double A = 0.0, P = 0.0;
        for (int s = 0; s < waveu; ++s) {
            double dT = (double)tsg[(s + 1) * SEG] - (double)tsg[s * SEG];
            P += dPx[s * 64 + lane] + A * dT;
            A += dAx[s * 64 + lane];
        }
        int fk = INT_MAX; double fA = 0.0, fP = 0.0;
        for (int c = 0; c < SEG; c += 11) {
            int so[11]; float buf[11]; double zc[11], dtc[11], zfc[11];
            #pragma unroll
            for (int i = 0; i < 11; ++i) so[i] = ordg[k0 + c + i];
            #pragma unroll
            for (int i = 0; i < 11; ++i) buf[i] = wT[so[i] * OUT_FEATURES + o];
            #pragma unroll
            for (int i = 0; i < 11; ++i) { double2 zd = zdtg[k0 + c + i];
                                           zc[i] = zd.x; dtc[i] = zd.y; }
            #pragma unroll
            for (int i = 0; i < 11; ++i) zfc[i] = zfg[k0 + c + i];
            #pragma unroll
            for (int i = 0; i < 11; ++i) {
                double w = (double)buf[i];
                A = fma(w, zc[i], A);
                P = fma(A, dtc[i], P);
                bool fire = (fk == INT_MAX) & (A > 1e-10) & (P >= zfc[i]);
                if (fire) { fk = k0 + c + i; fA = A; fP = P; }   // -> cndmask
            }
        }
        fkx[waveu * 64 + lane] = fk;
        fAx[waveu * 64 + lane] = fA;
        fPx[waveu * 64 + lane] = fP;
        if (waveu == NSEG - 1) { endA[lane] = A; endP[lane] = P; }  // totals
    }
    __syncthreads();

    // ---- final: wave 0, one lane per o ----
    if (waveu == 0) {
        int gk = INT_MAX; double gA = 0.0, gP = 0.0;
        #pragma unroll
        for (int s = 0; s < NSEG; ++s) {
            int k = fkx[s * 64 + lane];
            if (k < gk) { gk = k; gA = fAx[s * 64 + lane]; gP = fPx[s * 64 + lane]; }
        }
        bool done = (gk < NCOL);

        double AA, BB, tk, tn;
        bool have;
        if (done) {                       // fire k <= NCOL-2: real window
            AA = gA;
            tk = (double)tsg[gk];
            tn = (double)tsg[gk + 1];
            BB = fma(AA, tn, -gP);        // B = A*t_{k+1} - P
            have = true;
        } else {                          // last window k = NCOL-1
            AA = endA[lane];
            BB = fma(AA, 1000.0, -endP[lane]);   // P_tot = A*1000 - B
            tk = (double)tsg[NCOL - 1];
            tn = 1000.0;
            have = (AA > 1e-10);
        }

        float result = 1000.0f;
        bool need_fb = false;
        if (have) {
            double boa = BB / AA;
            double arg = -exp(fmin(boa, 80.0)) / AA;
            if (arg >= MIN_W_ARG) {
                double wl = lambertw0(fmin(fmax(arg, MIN_W_ARG), 0.0));
                double tc = boa - wl;
                if (tc >= tk && tc <= tn) result = (float)tc;
                else need_fb = done;
            } else need_fb = done;
        }

        // exact serial fallback (fp-boundary safety net; never taken)
        if (__ballot(need_fb) != 0ULL) {
            double A2 = gA, B2 = fma(gA, (double)tsg[gk + 1], -gP);
            for (int k = gk + 1; k < NCOL && k >= 0; ++k) {
                if (!need_fb) break;
                double w = (double)wT[ordg[k] * OUT_FEATURES + o];
                A2 = fma(w, zg[k], A2);
                B2 = fma(w, ztg[k], B2);
                if (!(A2 > 1e-10)) continue;
                double tkk = (double)tsg[k];
                double tnn = (k == NCOL - 1) ? 1000.0 : (double)tsg[k + 1];
                double boa = B2 / A2;
                double arg = -exp(fmin(boa, 80.0)) / A2;
                if (arg >= MIN_W_ARG) {
                    double wl = lambertw0(fmin(fmax(arg, MIN_W_ARG), 0.0));
                    double tc = boa - wl;
                    if (tc >= tkk && tc <= tnn) { result = (float)tc; need_fb = false; }
                }
            }
        }
        out[b * OUT_FEATURES + o] = result;
    }
}

// --------------------------------- launcher ----------------------------------
extern "C" void kernel_launch(void* const* d_in, const int* in_sizes, int n_in,
                              void* d_out, int out_size, void* d_ws, size_t ws_size,
                              hipStream_t stream) {
    const float* x      = (const float*)d_in[0];
    const float* weight = (const float*)d_in[1];
    const float* pulse  = (const float*)d_in[2];
    float* out = (float*)d_out;

    char* ws = (char*)d_ws;
    float* wT = (float*)ws;                               // 1034*512*4 B
    char*  tbl = ws + (size_t)NCOL * OUT_FEATURES * 4;    // 32 * 52224 B

    hipLaunchKernelGGL(prep_kernel, dim3(PREP_BLOCKS), dim3(256), 0, stream,
                       weight, wT, x, pulse, tbl);
    hipLaunchKernelGGL(solve_kernel, dim3(BATCH * OUT_FEATURES / 64), dim3(1024), 0, stream,
                       wT, tbl, out);
}

// Round 11
// 85.671 us; speedup vs baseline: 1.1818x; 1.0486x over previous
//
#include <hip/hip_runtime.h>
#include <math.h>
#include <limits.h>

#define IN_FEATURES 1024
#define OUT_FEATURES 512
#define N_PULSE 10
#define NCOL 1034
#define BATCH 32
#define MIN_W_ARG -0.3678794411714423

#define NSEG 16
#define SEG 66                          /* 16*66 = 1056 scan steps */
#define TBLN 1088                       /* table entries (>= 1056+1, 16-mult) */

/* packed per-b table: [ord i32 TBLN][ts f32 TBLN][z f64 TBLN][zt f64 TBLN] */
#define OFF_TS  (TBLN * 4)
#define OFF_Z   (TBLN * 8)
#define OFF_ZT  (TBLN * 16)
#define TBL_BYTES (TBLN * 24)           /* 26112 */

#define PREP_T_BLOCKS 136               /* 17 n-tiles x 8 o-tiles */
#define PREP_BLOCKS (PREP_T_BLOCKS + BATCH)

/* rank-block LDS layout (bytes) */
#define R_KM   0                        /* u32 monotone keys [1034] */
#define R_KF   4136                     /* f32 t             [1034] */
#define R_SIDX 8272                     /* i32 slot->elem    [1034] */
#define R_BASE 12408                    /* i32 bucket base   [1025] */
#define R_RUN  16508                    /* i32 running ptr   [1024] */
#define R_PS   20604                    /* i32 scan temp     [256]  */
#define R_BYTES 21632

// ---------- Kernel 1 (prep): transpose | counting-sort rank + z tables -------
__global__ __launch_bounds__(256, 1) void prep_kernel(
        const float* __restrict__ w, float* __restrict__ wT,
        const float* __restrict__ x, const float* __restrict__ pulse,
        char* __restrict__ tbl) {
    __shared__ __align__(16) char smem_u[R_BYTES];   // >= transpose tile 16640
    const int tid = threadIdx.x;

    if (blockIdx.x < PREP_T_BLOCKS) {
        // ---- tiled transpose [O,N] -> [N,O], coalesced both ways ----
        float (*tile)[65] = (float (*)[65])smem_u;
        const int n0 = (blockIdx.x % 17) * 64;
        const int o0 = (blockIdx.x / 17) * 64;
        const int tx = tid & 63, ty = tid >> 6;
        #pragma unroll
        for (int r = 0; r < 16; ++r) {
            int ol = r * 4 + ty, n = n0 + tx;
            if (n < NCOL) tile[ol][tx] = w[(o0 + ol) * NCOL + n];
        }
        __syncthreads();
        #pragma unroll
        for (int r = 0; r < 16; ++r) {
            int nl = r * 4 + ty, n = n0 + nl;
            if (n < NCOL) wT[n * OUT_FEATURES + o0 + tx] = tile[tx][nl];
        }
    } else {
        // ---- counting-sort stable argsort for batch row b ----
        unsigned*  km   = (unsigned*)(smem_u + R_KM);
        float*     kf   = (float*)(smem_u + R_KF);
        int*       sidx = (int*)(smem_u + R_SIDX);
        int*       base = (int*)(smem_u + R_BASE);
        int*       run  = (int*)(smem_u + R_RUN);
        int*       ps   = (int*)(smem_u + R_PS);
        const int b = blockIdx.x - PREP_T_BLOCKS;

        for (int e = tid; e < NCOL; e += 256) {
            float t = (e < IN_FEATURES) ? x[b * IN_FEATURES + e]
                                        : pulse[e - IN_FEATURES];
            kf[e] = t;
            unsigned u = __float_as_uint(t);
            km[e] = (u & 0x80000000u) ? ~u : (u | 0x80000000u);
        }
        for (int i = tid; i < 1024; i += 256) run[i] = 0;
        __syncthreads();

        // histogram: bucket(t) = min(1023, t*1024) is monotone in t
        for (int e = tid; e < NCOL; e += 256) {
            int bk = min(1023, max(0, (int)(kf[e] * 1024.0f)));
            atomicAdd(&run[bk], 1);
        }
        __syncthreads();

        // exclusive prefix over 1024 counts (4 per thread + block scan)
        int c4[4], v = 0;
        #pragma unroll
        for (int j = 0; j < 4; ++j) { c4[j] = run[4 * tid + j]; v += c4[j]; }
        ps[tid] = v;
        __syncthreads();
        for (int off = 1; off < 256; off <<= 1) {
            int xv = (tid >= off) ? ps[tid - off] : 0;
            __syncthreads();
            ps[tid] += xv;
            __syncthreads();
        }
        int ex = ps[tid] - v;
        #pragma unroll
        for (int j = 0; j < 4; ++j) { base[4 * tid + j] = ex; ex += c4[j]; }
        if (tid == 255) base[1024] = ex;            // == NCOL
        __syncthreads();
        for (int i = tid; i < 1024; i += 256) run[i] = base[i];
        __syncthreads();

        // scatter (arbitrary intra-bucket order)
        for (int e = tid; e < NCOL; e += 256) {
            int bk = min(1023, max(0, (int)(kf[e] * 1024.0f)));
            int slot = atomicAdd(&run[bk], 1);
            sidx[slot] = e;
        }
        __syncthreads();

        // exact stable rank within bucket + global table write
        char* gb = tbl + b * TBL_BYTES;
        int*    ordg = (int*)gb;
        float*  tsg  = (float*)(gb + OFF_TS);
        double* zg   = (double*)(gb + OFF_Z);
        double* ztg  = (double*)(gb + OFF_ZT);

        for (int s = tid; s < NCOL; s += 256) {
            int e = sidx[s];
            float t = kf[e];
            unsigned u = km[e];
            int bk = min(1023, max(0, (int)(t * 1024.0f)));
            int lo = base[bk], hi = base[bk + 1];
            int r = lo;
            for (int j = lo; j < hi; ++j) {         // avg 1 element per bucket
                int ej = sidx[j];
                unsigned uj = km[ej];
                r += (uj < u) || (uj == u && ej < e);
            }
            double zv = exp((double)t);
            ordg[r] = e; tsg[r] = t; zg[r] = zv; ztg[r] = zv * (double)t;
        }
        for (int p = NCOL + tid; p < TBLN; p += 256) {
            ordg[p] = 0; tsg[p] = -1.0f; zg[p] = 0.0; ztg[p] = 0.0;
            // pad ts=-1: scan's fire test provably false on pad steps
        }
    }
}

// ------------------------- Lambert W0 on [-1/e, 0] ---------------------------
__device__ __forceinline__ double lambertw0(double xx) {
    const double e = 2.718281828459045;
    double w = (xx < -0.25) ? (-1.0 + sqrt(fmax(2.0 * (1.0 + e * xx), 0.0)))
                            : xx * (1.0 - xx);
    #pragma unroll 4
    for (int i = 0; i < 12; ++i) {
        double ew = exp(w);
        double f  = w * ew - xx;
        double denom = ew * (w + 1.0) - (w + 2.0) * f / (2.0 * (w + 1.0) + 1e-12);
        w = w - f / (denom + 1e-12);
    }
    return w;
}

// ------------- Kernel 2: segmented two-pass scan, 16 waves/block -------------
// pass1: per-segment (dA,dB) partial sums; LDS exchange (cumsum linearity)
// pass2: rescan own 66-step segment with exclusive prefix; first filter-fire
//        (fire = A>1e-10 && A*t_{k+1}-B >= z_{k+1}; V rising on window,
//         entry condition implied by previous window's exit failing)
// final: wave 0 picks earliest segment fire, ONE Lambert + exact reference
//        check; exact serial fallback for fp-boundary safety (never taken).
__global__ __launch_bounds__(1024) void solve_kernel(
        const float* __restrict__ wT,
        const char* __restrict__ tbl,
        float* __restrict__ out) {
    __shared__ char smem[TBL_BYTES];
    __shared__ double segA[NSEG * 64], segB[NSEG * 64];
    __shared__ int    sfk[NSEG * 64];
    __shared__ double sfA[NSEG * 64], sfB[NSEG * 64];

    const int b = blockIdx.x >> 3;
    const int o0 = (blockIdx.x & 7) << 6;
    const int wave = threadIdx.x >> 6;
    const int lane = threadIdx.x & 63;
    const int o = o0 + lane;

    {
        const uint4* g = (const uint4*)(tbl + b * TBL_BYTES);
        uint4* l = (uint4*)smem;
        for (int e = threadIdx.x; e < TBL_BYTES / 16; e += 1024) l[e] = g[e];
    }
    __syncthreads();
    const int*    ord_l = (const int*)smem;
    const float*  ts_l  = (const float*)(smem + OFF_TS);
    const double* z_l   = (const double*)(smem + OFF_Z);
    const double* zt_l  = (const double*)(smem + OFF_ZT);

    const int k0 = wave * SEG;

    // ---- pass 1: segment partial sums ----
    {
        double a0 = 0.0, a1 = 0.0, b0 = 0.0, b1 = 0.0;
        for (int c = 0; c < SEG; c += 11) {
            int idx[11]; float buf[11];
            #pragma unroll
            for (int i = 0; i < 11; ++i) idx[i] = ord_l[k0 + c + i];
            #pragma unroll
            for (int i = 0; i < 11; ++i) buf[i] = wT[idx[i] * OUT_FEATURES + o];
            #pragma unroll
            for (int i = 0; i < 11; ++i) {
                double w = (double)buf[i];
                if (i & 1) { a1 = fma(w, z_l[k0 + c + i], a1);
                             b1 = fma(w, zt_l[k0 + c + i], b1); }
                else       { a0 = fma(w, z_l[k0 + c + i], a0);
                             b0 = fma(w, zt_l[k0 + c + i], b0); }
            }
        }
        segA[wave * 64 + lane] = a0 + a1;
        segB[wave * 64 + lane] = b0 + b1;
    }
    __syncthreads();

    // ---- pass 2: rescan own segment with exclusive prefix offset ----
    {
        double A = 0.0, Bv = 0.0;
        for (int s = 0; s < wave; ++s) {
            A  += segA[s * 64 + lane];
            Bv += segB[s * 64 + lane];
        }
        int fk = INT_MAX; double fA = 0.0, fB = 0.0;
        for (int c = 0; c < SEG; c += 11) {
            int idx[11]; float buf[11];
            #pragma unroll
            for (int i = 0; i < 11; ++i) idx[i] = ord_l[k0 + c + i];
            #pragma unroll
            for (int i = 0; i < 11; ++i) buf[i] = wT[idx[i] * OUT_FEATURES + o];
            #pragma unroll
            for (int i = 0; i < 11; ++i) {
                int k = k0 + c + i;
                double w = (double)buf[i];
                A  = fma(w, z_l[k],  A);
                Bv = fma(w, zt_l[k], Bv);
                bool fire = (fk == INT_MAX) & (A > 1e-10) &
                            (fma(A, (double)ts_l[k + 1], -Bv) >= z_l[k + 1]);
                if (fire) { fk = k; fA = A; fB = Bv; }
            }
        }
        sfk[wave * 64 + lane] = fk;
        sfA[wave * 64 + lane] = fA;
        sfB[wave * 64 + lane] = fB;
    }
    __syncthreads();

    // ---- final: wave 0, one lane per o ----
    if (wave == 0) {
        int gk = INT_MAX; double gA = 0.0, gB = 0.0;
        #pragma unroll
        for (int s = 0; s < NSEG; ++s) {
            int k = sfk[s * 64 + lane];
            if (k < gk) { gk = k; gA = sfA[s * 64 + lane]; gB = sfB[s * 64 + lane]; }
        }
        bool done = (gk < NCOL);

        double AA, BB, tk, tn;
        bool have;
        if (done) {
            AA = gA; BB = gB;
            tk = (double)ts_l[gk];
            tn = (double)ts_l[gk + 1];
            have = true;
        } else {
            double tA = 0.0, tB = 0.0;
            #pragma unroll
            for (int s = 0; s < NSEG; ++s) { tA += segA[s * 64 + lane]; tB += segB[s * 64 + lane]; }
            AA = tA; BB = tB;
            tk = (double)ts_l[NCOL - 1];
            tn = 1000.0;
            have = (AA > 1e-10);
        }

        float result = 1000.0f;
        bool need_fb = false;
        if (have) {
            double boa = BB / AA;
            double arg = -exp(fmin(boa, 80.0)) / AA;
            if (arg >= MIN_W_ARG) {
                double wl = lambertw0(fmin(fmax(arg, MIN_W_ARG), 0.0));
                double tc = boa - wl;
                if (tc >= tk && tc <= tn) result = (float)tc;
                else need_fb = done;
            } else need_fb = done;
        }

        if (__ballot(need_fb) != 0ULL) {
            double A2 = gA, B2 = gB;
            for (int k = gk + 1; k < NCOL && k >= 0; ++k) {
                if (!need_fb) break;
                double w = (double)wT[ord_l[k] * OUT_FEATURES + o];
                A2 = fma(w, z_l[k], A2);
                B2 = fma(w, zt_l[k], B2);
                if (!(A2 > 1e-10)) continue;
                double tkk = (double)ts_l[k];
                double tnn = (k == NCOL - 1) ? 1000.0 : (double)ts_l[k + 1];
                double boa = B2 / A2;
                double arg = -exp(fmin(boa, 80.0)) / A2;
                if (arg >= MIN_W_ARG) {
                    double wl = lambertw0(fmin(fmax(arg, MIN_W_ARG), 0.0));
                    double tc = boa - wl;
                    if (tc >= tkk && tc <= tnn) { result = (float)tc; need_fb = false; }
                }
            }
        }
        out[b * OUT_FEATURES + o] = result;
    }
}

// --------------------------------- launcher ----------------------------------
extern "C" void kernel_launch(void* const* d_in, const int* in_sizes, int n_in,
                              void* d_out, int out_size, void* d_ws, size_t ws_size,
                              hipStream_t stream) {
    const float* x      = (const float*)d_in[0];
    const float* weight = (const float*)d_in[1];
    const float* pulse  = (const float*)d_in[2];
    float* out = (float*)d_out;

    char* ws = (char*)d_ws;
    float* wT = (float*)ws;                               // 1034*512*4 B
    char*  tbl = ws + (size_t)NCOL * OUT_FEATURES * 4;    // 32 * 26112 B

    hipLaunchKernelGGL(prep_kernel, dim3(PREP_BLOCKS), dim3(256), 0, stream,
                       weight, wT, x, pulse, tbl);
    hipLaunchKernelGGL(solve_kernel, dim3(BATCH * OUT_FEATURES / 64), dim3(1024), 0, stream,
                       wT, tbl, out);
}